// Round 5
// baseline (771.082 us; speedup 1.0000x reference)
//
#include <hip/hip_runtime.h>

namespace {

constexpr int N = 2048;
constexpr int D = 64;
constexpr float SCALE = 0.125f;   // D^-0.5
constexpr int LK = 72;            // k_s/s_s row stride (shorts): 16B-aligned rows (b128 reads)
constexpr int LV = 68;            // vt_s row stride (shorts): 8B-aligned rows
constexpr int NT = N / 64;        // 32 K-tiles

typedef __attribute__((ext_vector_type(8))) short bf16x8;   // MFMA A/B frag
typedef __attribute__((ext_vector_type(4))) short short4v;  // b64 LDS packet
typedef __attribute__((ext_vector_type(2))) short short2v;
typedef __attribute__((ext_vector_type(4))) float f32x4;    // MFMA C/D frag
typedef __attribute__((ext_vector_type(4))) int   int4v;    // mask packet

__device__ inline short f2bf(float x) {
  union { float f; unsigned u; } a; a.f = x;
  unsigned r = a.u + 0x7fffu + ((a.u >> 16) & 1u);
  return (short)(r >> 16);
}

#if __has_builtin(__builtin_amdgcn_cvt_pk_bf16_f32)
typedef __attribute__((ext_vector_type(2))) __bf16 bfv2;
__device__ inline short2v pk_bf(float lo, float hi) {
  bfv2 t = __builtin_amdgcn_cvt_pk_bf16_f32(lo, hi);
  return __builtin_bit_cast(short2v, t);
}
#else
__device__ inline short2v pk_bf(float lo, float hi) {
  short2v r; r[0] = f2bf(lo); r[1] = f2bf(hi); return r;
}
#endif

__device__ inline short4v pk4(float4 f) {
  short2v a = pk_bf(f.x, f.y), b = pk_bf(f.z, f.w);
  short4v r; r[0] = a[0]; r[1] = a[1]; r[2] = b[0]; r[3] = b[1];
  return r;
}

__device__ inline float fast_tanh(float x) {
  // tanh(x) = 1 - 2/(exp2(x*2log2e)+1); correct limits at +-inf
  float e = __builtin_amdgcn_exp2f(x * 2.885390081777927f);
  return 1.0f - 2.0f * __builtin_amdgcn_rcpf(e + 1.0f);
}

} // namespace

// One block = one (b,h) x 64-row Q tile; 4 waves, wave w owns q rows [16w,16w+16).
// Double-buffered K/V LDS -> ONE barrier per K-tile. Per iteration:
//   barrier; issue global loads for tile kt+1 (regs); compute tile kt
//   (QK^T-swapped MFMA, tanh, mask, s_s round-trip, PV MFMA);
//   convert+write tile kt+1 regs -> other LDS buffer (load wait lands here,
//   ~600 cyc after issue). The barrier drains already-complete loads.
__global__ __launch_bounds__(256) void attn_tanh_kernel(
    const float* __restrict__ Q, const float* __restrict__ K,
    const float* __restrict__ V, const int* __restrict__ M,
    float* __restrict__ O)
{
  __shared__ __align__(16) short k_s[2][64 * LK];
  __shared__ __align__(16) short vt_s[2][64 * LV];  // V transposed: [d][kpos]
  __shared__ __align__(16) short s_s[64 * LK];

  const int tid  = threadIdx.x;
  const int wave = tid >> 6;
  const int lane = tid & 63;
  const int l15  = lane & 15;
  const int quad = lane >> 4;

  const int bh = blockIdx.x >> 5;
  const int q0 = (blockIdx.x & 31) * 64;

  const float* qp = Q + (size_t)bh * N * D;
  const float* kp = K + (size_t)bh * N * D;
  const float* vp = V + (size_t)bh * N * D;
  const int*   mp = M + (size_t)bh * N * N;
  float* op = O + (size_t)bh * N * D;

  // ---- Q B-fragments in registers for all 32 tiles ----
  bf16x8 qf[2];
  {
    const float* qrow = qp + (size_t)(q0 + wave * 16 + l15) * D + quad * 8;
#pragma unroll
    for (int ks = 0; ks < 2; ++ks) {
      float4 f0 = *(const float4*)(qrow + ks * 32);
      float4 f1 = *(const float4*)(qrow + ks * 32 + 4);
      short4v lo = pk4(f0), hi = pk4(f1);
      bf16x8 t;
      t[0]=lo[0]; t[1]=lo[1]; t[2]=lo[2]; t[3]=lo[3];
      t[4]=hi[0]; t[5]=hi[1]; t[6]=hi[2]; t[7]=hi[3];
      qf[ks] = t;
    }
  }

  const int r0 = tid >> 4;         // K staging row sub-index 0..15
  const int c4 = (tid & 15) << 2;  // K staging d-offset

  const float* vbase = vp + (size_t)(wave * 16) * D + lane;  // lane = d
  const int*   mbase = mp + (size_t)(q0 + wave * 16 + l15) * N + quad * 4;

  float4 kA[4], kB[4];
  float  vA[16], vB[16];
  int4v  mA[4], mB[4];

  auto issue_loads = [&](int kt1, float4* kr, float* vr, int4v* mr) {
    const float* kpt = kp + (size_t)kt1 * 64 * D;
#pragma unroll
    for (int i = 0; i < 4; ++i)
      kr[i] = *(const float4*)(kpt + (size_t)(i * 16 + r0) * D + c4);
    const float* vpt = vbase + (size_t)kt1 * 64 * D;
#pragma unroll
    for (int i = 0; i < 16; ++i)
      vr[i] = vpt[(size_t)i * D];
    const int* mb = mbase + (size_t)kt1 * 64;
#pragma unroll
    for (int ct = 0; ct < 4; ++ct)
      mr[ct] = __builtin_nontemporal_load((const int4v*)(mb + ct * 16));
  };

  auto write_kv = [&](int buf, const float4* kr, const float* vr) {
#pragma unroll
    for (int i = 0; i < 4; ++i)
      *(short4v*)(&k_s[buf][(i * 16 + r0) * LK + c4]) = pk4(kr[i]);
#pragma unroll
    for (int c = 0; c < 4; ++c) {
      short2v p0 = pk_bf(vr[4 * c + 0], vr[4 * c + 1]);
      short2v p1 = pk_bf(vr[4 * c + 2], vr[4 * c + 3]);
      short4v vv; vv[0] = p0[0]; vv[1] = p0[1]; vv[2] = p1[0]; vv[3] = p1[1];
      *(short4v*)(&vt_s[buf][lane * LV + wave * 16 + 4 * c]) = vv;
    }
  };

  f32x4 o_acc[4];
#pragma unroll
  for (int i = 0; i < 4; ++i) o_acc[i] = (f32x4){0.f, 0.f, 0.f, 0.f};

  auto compute = [&](int buf, const int4v* mr) {
    const short* ks_ = k_s[buf];
    const short* vs_ = vt_s[buf];
    // S^T = K Q^T (operand swap); C layout: lane(quad,l15) reg r = S[q=l15][kp=ct*16+quad*4+r]
#pragma unroll
    for (int ct = 0; ct < 4; ++ct) {
      f32x4 acc = {0.f, 0.f, 0.f, 0.f};
#pragma unroll
      for (int ksi = 0; ksi < 2; ++ksi) {
        bf16x8 a = *(const bf16x8*)(&ks_[(ct * 16 + l15) * LK + ksi * 32 + quad * 8]);
        acc = __builtin_amdgcn_mfma_f32_16x16x32_bf16(a, qf[ksi], acc, 0, 0, 0);
      }
      float s0 = mr[ct][0] ? 0.f : fast_tanh(acc[0] * SCALE);
      float s1 = mr[ct][1] ? 0.f : fast_tanh(acc[1] * SCALE);
      float s2 = mr[ct][2] ? 0.f : fast_tanh(acc[2] * SCALE);
      float s3 = mr[ct][3] ? 0.f : fast_tanh(acc[3] * SCALE);
      short2v p0 = pk_bf(s0, s1), p1 = pk_bf(s2, s3);
      short4v sv; sv[0] = p0[0]; sv[1] = p0[1]; sv[2] = p1[0]; sv[3] = p1[1];
      *(short4v*)(&s_s[(wave * 16 + l15) * LK + ct * 16 + quad * 4]) = sv;
    }
    // O += S V  (s_s is wave-local: no barrier, compiler handles lgkmcnt)
#pragma unroll
    for (int ksi = 0; ksi < 2; ++ksi) {
      bf16x8 a = *(const bf16x8*)(&s_s[(wave * 16 + l15) * LK + ksi * 32 + quad * 8]);
#pragma unroll
      for (int nt = 0; nt < 4; ++nt) {
        const short* vb = &vs_[(nt * 16 + l15) * LV + ksi * 32 + quad * 8];
        short4v lo = *(const short4v*)(vb);
        short4v hi = *(const short4v*)(vb + 4);
        bf16x8 b = __builtin_shufflevector(lo, hi, 0, 1, 2, 3, 4, 5, 6, 7);
        o_acc[nt] = __builtin_amdgcn_mfma_f32_16x16x32_bf16(a, b, o_acc[nt], 0, 0, 0);
      }
    }
  };

  // ---- prologue: tile 0 -> regs A -> LDS buf 0 ----
  issue_loads(0, kA, vA, mA);
  write_kv(0, kA, vA);

  // ---- main loop, unrolled x2 (NT even). One barrier per tile. ----
  for (int kt = 0; kt < NT; kt += 2) {
    // even tile kt: data in buf0, mask in mA
    __syncthreads();
    issue_loads(kt + 1, kB, vB, mB);     // kt+1 <= 31 always valid
    compute(0, mA);
    write_kv(1, kB, vB);

    // odd tile kt+1: data in buf1, mask in mB
    __syncthreads();
    if (kt + 2 < NT) issue_loads(kt + 2, kA, vA, mA);
    compute(1, mB);
    if (kt + 2 < NT) write_kv(0, kA, vA);
  }

  // ---- write O (C layout: row q = quad*4+r, col d = nt*16+l15) ----
#pragma unroll
  for (int nt = 0; nt < 4; ++nt) {
#pragma unroll
    for (int r = 0; r < 4; ++r) {
      op[(q0 + wave * 16 + quad * 4 + r) * D + nt * 16 + l15] = o_acc[nt][r];
    }
  }
}

extern "C" void kernel_launch(void* const* d_in, const int* in_sizes, int n_in,
                              void* d_out, int out_size, void* d_ws, size_t ws_size,
                              hipStream_t stream) {
  const float* q = (const float*)d_in[0];
  const float* k = (const float*)d_in[1];
  const float* v = (const float*)d_in[2];
  const int* m = (const int*)d_in[3];   // harness promotes bool -> int32
  float* out = (float*)d_out;

  attn_tanh_kernel<<<dim3(1024), dim3(256), 0, stream>>>(q, k, v, m, out);
}

// Round 6
// 763.336 us; speedup vs baseline: 1.0101x; 1.0101x over previous
//
#include <hip/hip_runtime.h>

namespace {

constexpr int N = 2048;
constexpr int D = 64;
constexpr float SCALE = 0.125f;   // D^-0.5
constexpr int LK = 72;            // k_s / s_s row stride (shorts): 16B-aligned rows for b128 reads
constexpr int LV = 68;            // vt_s row stride (shorts): 8B-aligned rows
constexpr int NT = N / 64;        // 32 K-tiles

typedef __attribute__((ext_vector_type(8))) short bf16x8;   // MFMA A/B frag
typedef __attribute__((ext_vector_type(4))) short short4v;  // b64 LDS packet
typedef __attribute__((ext_vector_type(2))) short short2v;
typedef __attribute__((ext_vector_type(4))) float f32x4;    // MFMA C/D frag
typedef __attribute__((ext_vector_type(4))) int   int4v;    // mask packet

__device__ inline short f2bf(float x) {
  union { float f; unsigned u; } a; a.f = x;
  unsigned r = a.u + 0x7fffu + ((a.u >> 16) & 1u);
  return (short)(r >> 16);
}

#if __has_builtin(__builtin_amdgcn_cvt_pk_bf16_f32)
typedef __attribute__((ext_vector_type(2))) __bf16 bfv2;
__device__ inline short2v pk_bf(float lo, float hi) {
  bfv2 t = __builtin_amdgcn_cvt_pk_bf16_f32(lo, hi);
  return __builtin_bit_cast(short2v, t);
}
#else
__device__ inline short2v pk_bf(float lo, float hi) {
  short2v r; r[0] = f2bf(lo); r[1] = f2bf(hi); return r;
}
#endif

__device__ inline short4v pk4(float4 f) {
  short2v a = pk_bf(f.x, f.y), b = pk_bf(f.z, f.w);
  short4v r; r[0] = a[0]; r[1] = a[1]; r[2] = b[0]; r[3] = b[1];
  return r;
}

__device__ inline float fast_tanh(float x) {
  // tanh(x) = 1 - 2/(exp2(x*2log2e)+1); correct limits at +-inf
  float e = __builtin_amdgcn_exp2f(x * 2.885390081777927f);
  return 1.0f - 2.0f * __builtin_amdgcn_rcpf(e + 1.0f);
}

} // namespace

// One block = one (b,h) x 64-row Q tile; 4 waves, wave w owns q rows [16w,16w+16).
// R4 structure (single staging reg set, register prefetch of tile kt+1 issued
// mid-compute of tile kt, 36 KB LDS) + __launch_bounds__(256,4): force VGPR<=128
// so 4 blocks/CU are resident (16 waves/CU) — more overlapping load bursts to
// cover the mask-stream latency that holds HBM at ~2 TB/s.
__global__ __launch_bounds__(256, 4) void attn_tanh_kernel(
    const float* __restrict__ Q, const float* __restrict__ K,
    const float* __restrict__ V, const int* __restrict__ M,
    float* __restrict__ O)
{
  __shared__ __align__(16) short k_s[64 * LK];
  __shared__ __align__(16) short s_s[64 * LK];
  __shared__ __align__(16) short vt_s[64 * LV];   // V transposed: [d][kpos]

  const int tid  = threadIdx.x;
  const int wave = tid >> 6;
  const int lane = tid & 63;
  const int l15  = lane & 15;
  const int quad = lane >> 4;

  const int bh = blockIdx.x >> 5;
  const int q0 = (blockIdx.x & 31) * 64;

  const float* qp = Q + (size_t)bh * N * D;
  const float* kp = K + (size_t)bh * N * D;
  const float* vp = V + (size_t)bh * N * D;
  const int*   mp = M + (size_t)bh * N * N;
  float* op = O + (size_t)bh * N * D;

  // ---- Q B-fragments in registers for all 32 tiles ----
  bf16x8 qf[2];
  {
    const float* qrow = qp + (size_t)(q0 + wave * 16 + l15) * D + quad * 8;
#pragma unroll
    for (int ks = 0; ks < 2; ++ks) {
      float4 f0 = *(const float4*)(qrow + ks * 32);
      float4 f1 = *(const float4*)(qrow + ks * 32 + 4);
      short4v lo = pk4(f0), hi = pk4(f1);
      bf16x8 t;
      t[0]=lo[0]; t[1]=lo[1]; t[2]=lo[2]; t[3]=lo[3];
      t[4]=hi[0]; t[5]=hi[1]; t[6]=hi[2]; t[7]=hi[3];
      qf[ks] = t;
    }
  }

  const int r0 = tid >> 4;         // K staging row sub-index 0..15
  const int c4 = (tid & 15) << 2;  // K staging d-offset

  float4 kreg[4];
  float  vreg[16];                 // V: lane = d, 16 consecutive kp rows
  int4v  mreg[4];

  const float* vbase = vp + (size_t)(wave * 16) * D + lane;
  const int*   mbase = mp + (size_t)(q0 + wave * 16 + l15) * N + quad * 4;

  // ---- prologue: loads for tile 0 ----
#pragma unroll
  for (int i = 0; i < 4; ++i)
    kreg[i] = *(const float4*)(kp + (size_t)(i * 16 + r0) * D + c4);
#pragma unroll
  for (int i = 0; i < 16; ++i)
    vreg[i] = vbase[(size_t)i * D];
#pragma unroll
  for (int ct = 0; ct < 4; ++ct)
    mreg[ct] = __builtin_nontemporal_load((const int4v*)(mbase + ct * 16));

  f32x4 o_acc[4];
#pragma unroll
  for (int i = 0; i < 4; ++i) o_acc[i] = (f32x4){0.f, 0.f, 0.f, 0.f};

  for (int kt = 0; kt < NT; ++kt) {
    __syncthreads();   // previous tile's k_s/vt_s readers done

    // ---- staged regs -> LDS (all b64) ----
#pragma unroll
    for (int i = 0; i < 4; ++i)
      *(short4v*)(&k_s[(i * 16 + r0) * LK + c4]) = pk4(kreg[i]);
#pragma unroll
    for (int c = 0; c < 4; ++c) {
      short2v p0 = pk_bf(vreg[4 * c + 0], vreg[4 * c + 1]);
      short2v p1 = pk_bf(vreg[4 * c + 2], vreg[4 * c + 3]);
      short4v vv; vv[0] = p0[0]; vv[1] = p0[1]; vv[2] = p1[0]; vv[3] = p1[1];
      *(short4v*)(&vt_s[lane * LV + wave * 16 + 4 * c]) = vv;
    }
    __syncthreads();

    // ---- S^T = K Q^T (operand swap), tanh, mask; b64-packed S write ----
#pragma unroll
    for (int ct = 0; ct < 4; ++ct) {
      f32x4 acc = {0.f, 0.f, 0.f, 0.f};
#pragma unroll
      for (int ksi = 0; ksi < 2; ++ksi) {
        bf16x8 a = *(const bf16x8*)(&k_s[(ct * 16 + l15) * LK + ksi * 32 + quad * 8]);
        acc = __builtin_amdgcn_mfma_f32_16x16x32_bf16(a, qf[ksi], acc, 0, 0, 0);
      }
      // C layout of S^T: lane(quad,l15) reg r = S[q=l15][kp=ct*16+quad*4+r]
      float s0 = mreg[ct][0] ? 0.f : fast_tanh(acc[0] * SCALE);
      float s1 = mreg[ct][1] ? 0.f : fast_tanh(acc[1] * SCALE);
      float s2 = mreg[ct][2] ? 0.f : fast_tanh(acc[2] * SCALE);
      float s3 = mreg[ct][3] ? 0.f : fast_tanh(acc[3] * SCALE);
      short2v p0 = pk_bf(s0, s1), p1 = pk_bf(s2, s3);
      short4v sv; sv[0] = p0[0]; sv[1] = p0[1]; sv[2] = p1[0]; sv[3] = p1[1];
      *(short4v*)(&s_s[(wave * 16 + l15) * LK + ct * 16 + quad * 4]) = sv;
    }

    // ---- prefetch tile kt+1 (issue only; consumed next iteration) ----
    if (kt + 1 < NT) {
      const float* kpt = kp + (size_t)(kt + 1) * 64 * D;
#pragma unroll
      for (int i = 0; i < 4; ++i)
        kreg[i] = *(const float4*)(kpt + (size_t)(i * 16 + r0) * D + c4);
      const float* vpt = vbase + (size_t)(kt + 1) * 64 * D;
#pragma unroll
      for (int i = 0; i < 16; ++i)
        vreg[i] = vpt[(size_t)i * D];
      const int* mb = mbase + (size_t)(kt + 1) * 64;
#pragma unroll
      for (int ct = 0; ct < 4; ++ct)
        mreg[ct] = __builtin_nontemporal_load((const int4v*)(mb + ct * 16));
    }

    // ---- O += S V  (s_s is wave-local: no barrier needed) ----
#pragma unroll
    for (int ksi = 0; ksi < 2; ++ksi) {
      bf16x8 a = *(const bf16x8*)(&s_s[(wave * 16 + l15) * LK + ksi * 32 + quad * 8]);
#pragma unroll
      for (int nt = 0; nt < 4; ++nt) {
        const short* vb = &vt_s[(nt * 16 + l15) * LV + ksi * 32 + quad * 8];
        short4v lo = *(const short4v*)(vb);
        short4v hi = *(const short4v*)(vb + 4);
        bf16x8 b = __builtin_shufflevector(lo, hi, 0, 1, 2, 3, 4, 5, 6, 7);
        o_acc[nt] = __builtin_amdgcn_mfma_f32_16x16x32_bf16(a, b, o_acc[nt], 0, 0, 0);
      }
    }
  }

  // ---- write O (C layout: row q = quad*4+r, col d = nt*16+l15) ----
#pragma unroll
  for (int nt = 0; nt < 4; ++nt) {
#pragma unroll
    for (int r = 0; r < 4; ++r) {
      op[(q0 + wave * 16 + quad * 4 + r) * D + nt * 16 + l15] = o_acc[nt][r];
    }
  }
}

extern "C" void kernel_launch(void* const* d_in, const int* in_sizes, int n_in,
                              void* d_out, int out_size, void* d_ws, size_t ws_size,
                              hipStream_t stream) {
  const float* q = (const float*)d_in[0];
  const float* k = (const float*)d_in[1];
  const float* v = (const float*)d_in[2];
  const int* m = (const int*)d_in[3];   // harness promotes bool -> int32
  float* out = (float*)d_out;

  attn_tanh_kernel<<<dim3(1024), dim3(256), 0, stream>>>(q, k, v, m, out);
}